// Round 10
// baseline (276.295 us; speedup 1.0000x reference)
//
#include <hip/hip_runtime.h>
#include <hip/hip_bf16.h>
#include <cstdint>
#include <cstddef>

// Problem constants
#define B_  4
#define S_  2048
#define D_  1024
#define H_  16
#define HD_ 64

typedef _Float16 half8  __attribute__((ext_vector_type(8)));
typedef _Float16 half4v __attribute__((ext_vector_type(4)));
typedef _Float16 half2v __attribute__((ext_vector_type(2)));
typedef float    f32x4  __attribute__((ext_vector_type(4)));
typedef unsigned int uint2v __attribute__((ext_vector_type(2)));
typedef unsigned int uint4v __attribute__((ext_vector_type(4)));

// async global->LDS, 16B per lane. LDS dest = wave-uniform base + lane*16.
__device__ __forceinline__ void async_copy16(const void* g, void* l) {
    __builtin_amdgcn_global_load_lds(
        (const __attribute__((address_space(1))) unsigned int*)g,
        (__attribute__((address_space(3))) unsigned int*)l,
        16, 0, 0);
}

__device__ __forceinline__ half8 hscale8(half8 v, _Float16 s) {
    #pragma unroll
    for (int i = 0; i < 8; ++i) v[i] *= s;
    return v;
}

// RNE f32x2 -> packed f16x2 (identical numerics to scalar (_Float16) casts)
__device__ __forceinline__ unsigned int pack2(float a, float b) {
    half2v h = { (_Float16)a, (_Float16)b };
    return __builtin_bit_cast(unsigned int, h);
}

// ---------------- prep kernels ----------------

__global__ void cast_x_kernel(const float4* __restrict__ in, half4v* __restrict__ out, int n4) {
    int i = blockIdx.x * 256 + threadIdx.x;
    if (i < n4) {
        float4 v = in[i];
        half4v h = { (_Float16)v.x, (_Float16)v.y, (_Float16)v.z, (_Float16)v.w };
        out[i] = h;
    }
}

// 4x fused: W [K=D][N=D] f32 row-major -> Wt [N][K] f16 row-major
__global__ void transpose_cast4_kernel(
    const float* __restrict__ W0, const float* __restrict__ W1,
    const float* __restrict__ W2, const float* __restrict__ W3,
    _Float16* __restrict__ T0, _Float16* __restrict__ T1,
    _Float16* __restrict__ T2, _Float16* __restrict__ T3)
{
    __shared__ float tile[32][33];
    const float* Wsel[4] = { W0, W1, W2, W3 };
    _Float16*    Tsel[4] = { T0, T1, T2, T3 };
    const float* W  = Wsel[blockIdx.z];
    _Float16*    Wt = Tsel[blockIdx.z];
    const int bn = blockIdx.x * 32, bk = blockIdx.y * 32;
    const int tx = threadIdx.x, ty = threadIdx.y;  // 32x8
    #pragma unroll
    for (int i = 0; i < 32; i += 8)
        tile[ty + i][tx] = W[(size_t)(bk + ty + i) * D_ + bn + tx];
    __syncthreads();
    #pragma unroll
    for (int i = 0; i < 32; i += 8)
        Wt[(size_t)(bn + ty + i) * D_ + bk + tx] = (_Float16)tile[tx][ty + i];
}

// ---------------- GEMM: C = relu(A @ Bt^T + bias) ----------------
// A [M][K] f16, Bt [N][K] f16.
// OUT_MODE: 0 = f32 [M][N] to C0;
//           3 = fused QKV: col segment 0->Q f16 [M][1024] (C0), 1->K f16 (C1),
//               2->V^T per head [(b*16+h)][hd][s] (C2); bias b0/b1/b2 per segment.
// 128x128 tile, BK=64, 256 threads = 4 waves (2x2 of 64x64).
// R10: REVERTED to R3/R8-verified structure after the 256^2 8-phase port
// measured 83 us / 620 TF (1 block/CU lockstep + 384-block tail at N=3072;
// the template's 1563 TF needs >=4 full dispatch rounds). This 32 KB
// single-buffer at ~5 blocks/CU hides staging via TLP (m114) and measures
// best at this shape. LDS XOR-swizzled: chunk c of row r at c^(r&7).
template<int OUT_MODE>
__global__ __launch_bounds__(256, 2) void gemm_bt_kernel(
    const _Float16* __restrict__ A, const _Float16* __restrict__ Bt,
    const float* __restrict__ b0, const float* __restrict__ b1,
    const float* __restrict__ b2,
    void* __restrict__ C0, void* __restrict__ C1, void* __restrict__ C2,
    int M, int N, int K)
{
    __shared__ _Float16 As[128 * 64];
    __shared__ _Float16 Bs[128 * 64];
    const int tid  = threadIdx.x;
    const int wid  = tid >> 6, lane = tid & 63;
    const int lr   = lane & 15, lq = lane >> 4;
    const int m0   = blockIdx.x * 128, n0 = blockIdx.y * 128;
    const int wm   = (wid >> 1) * 64, wn = (wid & 1) * 64;
    const int srow = tid >> 3;                        // 0..31
    const int csw  = ((tid & 7) ^ (srow & 7)) * 8;    // swizzled source col (halfs)

    f32x4 acc[4][4] = {};

    for (int k0 = 0; k0 < K; k0 += 64) {
        __syncthreads();
        #pragma unroll
        for (int i = 0; i < 4; ++i) {
            async_copy16(A  + (size_t)(m0 + i * 32 + srow) * K + k0 + csw,
                         (char*)As + (i * 256 + wid * 64) * 16);
            async_copy16(Bt + (size_t)(n0 + i * 32 + srow) * K + k0 + csw,
                         (char*)Bs + (i * 256 + wid * 64) * 16);
        }
        __syncthreads();
        #pragma unroll
        for (int ks = 0; ks < 2; ++ks) {
            half8 af[4], bf[4];
            #pragma unroll
            for (int t = 0; t < 4; ++t) {
                af[t] = *(const half8*)(As + (wm + t * 16 + lr) * 64 + (((ks * 4 + lq) ^ (lr & 7)) * 8));
                bf[t] = *(const half8*)(Bs + (wn + t * 16 + lr) * 64 + (((ks * 4 + lq) ^ (lr & 7)) * 8));
            }
            #pragma unroll
            for (int mt = 0; mt < 4; ++mt)
                #pragma unroll
                for (int nt = 0; nt < 4; ++nt)
                    acc[mt][nt] = __builtin_amdgcn_mfma_f32_16x16x32_f16(
                        af[mt], bf[nt], acc[mt][nt], 0, 0, 0);
        }
    }

    // n-segment is uniform per block (128 | 1024)
    const int seg = (OUT_MODE == 3) ? (n0 >> 10) : 0;
    const float* bp = (OUT_MODE == 3) ? (seg == 0 ? b0 : (seg == 1 ? b1 : b2)) : b0;

    #pragma unroll
    for (int mt = 0; mt < 4; ++mt) {
        const int row = m0 + wm + mt * 16 + lq * 4;   // + r
        #pragma unroll
        for (int nt = 0; nt < 4; ++nt) {
            const int col = n0 + wn + nt * 16 + lr;
            const int cl  = (OUT_MODE == 3) ? (col & 1023) : col;
            const float bb = bp[cl];
            if (OUT_MODE == 3 && seg == 2) {
                // V^T per head: [(b*16+h)][hd][s]; 4 consecutive s -> one 8B store
                const int b = row >> 11, sq = row & 2047;
                const int h = cl >> 6, hd = cl & 63;
                half4v o;
                #pragma unroll
                for (int r = 0; r < 4; ++r) {
                    float v = acc[mt][nt][r] + bb;
                    o[r] = (_Float16)(v > 0.0f ? v : 0.0f);
                }
                *(half4v*)((_Float16*)C2 +
                           ((size_t)(b * 16 + h) * 64 + hd) * S_ + sq) = o;
            } else if (OUT_MODE == 3) {
                _Float16* dst = (_Float16*)(seg ? C1 : C0);
                #pragma unroll
                for (int r = 0; r < 4; ++r) {
                    float v = acc[mt][nt][r] + bb;
                    dst[(size_t)(row + r) * 1024 + cl] = (_Float16)(v > 0.0f ? v : 0.0f);
                }
            } else {
                #pragma unroll
                for (int r = 0; r < 4; ++r) {
                    float v = acc[mt][nt][r] + bb;
                    ((float*)C0)[(size_t)(row + r) * N + col] = v > 0.0f ? v : 0.0f;
                }
            }
        }
    }
}

// ---------------- flash attention (8 waves/block, 2 frags/wave, 4 waves/SIMD) ----------------
// R10: attn was grid-capped at 2 waves/SIMD (512 blocks x 4 waves, MfmaUtil
// 21 / VALU 52 -> latency-exposed softmax chain). Same 512 blocks and same
// per-block work/iteration count as R8, but 8 waves/block (512 thr) with 2
// frags/wave -> 2 blocks/CU x 8 waves = 4 waves/SIMD. Per-block fixed costs
// unchanged (R2's penalty was from DOUBLING block iterations, not from
// 2-frag waves per se); only kf/bv LDS-read amortization halves (~+9% on
// that component, R2-measured). R2's 2-frag phase-split path measured 72
// VGPR -> fits the 128-reg budget of __launch_bounds__(512,4) without
// spill (R1 lesson: never cap below live set).
// Kept from R8: KVBLK=128, V as two [64][64] half-tiles (128B rows,
// chunk^(row&7), conflicts 0), in-register P via permlane swaps, bias
// folded into QK C-in, p-flip CU balance, XCD swizzle.
__global__ __launch_bounds__(512, 4) void attn_kernel(
    const _Float16* __restrict__ Qg, const _Float16* __restrict__ Kg,
    const _Float16* __restrict__ Vtg, _Float16* __restrict__ Y)
{
    __shared__ _Float16 Ks[2][128 * 64];     // K: [key 0..127][hd], 128B rows
    __shared__ _Float16 Vt[2][2][64 * 64];   // V: [half][hd][key-in-half], 128B rows

    // XCD swizzle: a head's 8 blocks share (i&7) -> same XCD L2 caches its K/V.
    const int i  = blockIdx.x;                 // 0..511
    const int bh = ((i & 7) << 3) | (i >> 6);  // 0..63
    const int praw = (i >> 3) & 7;
    const int p  = ((i >> 8) & 1) ? 7 - praw : praw;   // complementary pairing
    const int b  = bh >> 4, h = bh & 15;
    const int tid = threadIdx.x, wid = tid >> 6, lane = tid & 63;
    const int lr = lane & 15, lq = lane >> 4;

    const size_t base  = ((size_t)b * S_) * D_ + (size_t)h * HD_;   // Q/K/Y
    const _Float16* Vh = Vtg + (size_t)bh * 64 * S_;                // V^T head

    const int srow = tid >> 3;                       // 0..63 (8 lanes/row, 8 chunks)
    const int csw  = ((tid & 7) ^ (srow & 7)) * 8;   // swizzled SOURCE col (halfs)

    // 2 fragments per wave: slot wid of lo tile (rows 128p+) and hi tile
    // (rows 1920-128p+). Per-wave diag: +1 64-k tile for wid>=4.
    const int L = 128 * p, Hh = 1920 - 128 * p;
    const int qb[2] = { L + 16 * wid, Hh + 16 * wid };
    const int dk[2] = { 2 * p + (wid >> 2), 30 - 2 * p + (wid >> 2) };
    const int nSuper = 16 - p;                       // 128-key supertiles

    // Q fragments (B-operand rows [q][hd]) pre-scaled by log2(e)/8
    half8 aq[2][2];
    #pragma unroll
    for (int f = 0; f < 2; ++f) {
        const _Float16* qp = Qg + base + (size_t)(qb[f] + lr) * D_;
        aq[f][0] = hscale8(*(const half8*)(qp + lq * 8),      (_Float16)0.18033688f);
        aq[f][1] = hscale8(*(const half8*)(qp + 32 + lq * 8), (_Float16)0.18033688f);
    }

    float lsum[2] = {};
    f32x4 O[2][4] = {};
    half8 apf[2][2];   // in-register P fragments (PV A-operand)

    auto issue_super = [&](int sb) {
        const int bufi = sb & 1;
        // K: 2 calls x (512 lanes * 16B) = 128 rows of 128B
        #pragma unroll
        for (int ii = 0; ii < 2; ++ii)
            async_copy16(Kg + base + (size_t)(sb * 128 + ii * 64 + srow) * D_ + csw,
                         (char*)Ks[bufi] + (ii * 512 + wid * 64) * 16);
        // V: two [64][64] half-tiles, 1 call each (rows = hd 0..63)
        #pragma unroll
        for (int hh = 0; hh < 2; ++hh)
            async_copy16(Vh + (size_t)srow * S_ + sb * 128 + hh * 64 + csw,
                         (char*)Vt[bufi][hh] + (wid * 64) * 16);
    };

    issue_super(0);

    for (int sb = 0; sb < nSuper; ++sb) {
        const int cur = sb & 1;
        __syncthreads();   // buf[cur] loads done (issued one iter ago); WAR-safe
        if (sb + 1 < nSuper) issue_super(sb + 1);

        const _Float16* Kc = Ks[cur];

        #pragma unroll
        for (int hh = 0; hh < 2; ++hh) {
            const int kb = sb * 2 + hh;        // 64-key tile index
            const _Float16* Vc = Vt[cur][hh];

            // ---- phase 1: read kf once; QK + softmax + permlane per frag ----
            half8 kf[2][4];
            #pragma unroll
            for (int ks = 0; ks < 2; ++ks)
                #pragma unroll
                for (int tt = 0; tt < 4; ++tt)
                    kf[ks][tt] = *(const half8*)(Kc + (hh * 64 + tt * 16 + lr) * 64
                                                 + (((ks * 4 + lq) ^ (lr & 7)) * 8));

            #pragma unroll
            for (int f = 0; f < 2; ++f) {
                if (kb > dk[f]) continue;            // frag done (wave-uniform)

                // QK^T (C-in pre-biased with -4*log2e)
                f32x4 sc[4];
                #pragma unroll
                for (int tt = 0; tt < 4; ++tt)
                    sc[tt] = f32x4{ -5.770780f, -5.770780f, -5.770780f, -5.770780f };
                __builtin_amdgcn_s_setprio(1);
                #pragma unroll
                for (int ks = 0; ks < 2; ++ks)
                    #pragma unroll
                    for (int tt = 0; tt < 4; ++tt)
                        sc[tt] = __builtin_amdgcn_mfma_f32_16x16x32_f16(kf[ks][tt], aq[f][ks], sc[tt], 0, 0, 0);
                __builtin_amdgcn_s_setprio(0);

                // softmax (fixed normalizer, log2 domain; bias in sc)
                const bool diag = (kb == dk[f]);     // wave-uniform
                const int qg = qb[f] + lr;           // this lane's q
                const int kbase = kb * 64 + lq * 4;
                float sum = 0.0f;
                unsigned int pk[4][2];               // pk[t][d]: packed f16x2 of ev
                #pragma unroll
                for (int tt = 0; tt < 4; ++tt) {
                    float ev[4];
                    #pragma unroll
                    for (int r = 0; r < 4; ++r) {
                        float e = __builtin_amdgcn_exp2f(fminf(sc[tt][r], 15.8696f));
                        if (diag)
                            e = (kbase + tt * 16 + r <= qg) ? e : 0.0f;  // causal AFTER exp
                        ev[r] = e;
                        sum += e;
                    }
                    pk[tt][0] = pack2(ev[0], ev[1]);
                    pk[tt][1] = pack2(ev[2], ev[3]);
                }
                lsum[f] += sum;

                // in-register layout exchange (per 4-lane lq-group)
                #pragma unroll
                for (int ks = 0; ks < 2; ++ks) {
                    uint2v s1 = __builtin_amdgcn_permlane32_swap(pk[2 * ks][0], pk[2 * ks + 1][0], false, false);
                    uint2v s2 = __builtin_amdgcn_permlane16_swap(s1[0], s1[1], false, false);
                    uint2v u1 = __builtin_amdgcn_permlane32_swap(pk[2 * ks][1], pk[2 * ks + 1][1], false, false);
                    uint2v u2 = __builtin_amdgcn_permlane16_swap(u1[0], u1[1], false, false);
                    uint4v d = { s2[0], u2[0], s2[1], u2[1] };
                    apf[f][ks] = __builtin_bit_cast(half8, d);
                }
            }

            // ---- phase 2: read bv once; PV per frag (P from registers) ----
            half8 bv[2][4];
            #pragma unroll
            for (int ks = 0; ks < 2; ++ks)
                #pragma unroll
                for (int tt = 0; tt < 4; ++tt)
                    bv[ks][tt] = *(const half8*)(Vc + (tt * 16 + lr) * 64
                                                 + (((ks * 4 + lq) ^ (lr & 7)) * 8));

            #pragma unroll
            for (int f = 0; f < 2; ++f) {
                if (kb > dk[f]) continue;
                __builtin_amdgcn_s_setprio(1);
                #pragma unroll
                for (int ks = 0; ks < 2; ++ks)
                    #pragma unroll
                    for (int tt = 0; tt < 4; ++tt)
                        O[f][tt] = __builtin_amdgcn_mfma_f32_16x16x32_f16(apf[f][ks], bv[ks][tt], O[f][tt], 0, 0, 0);
                __builtin_amdgcn_s_setprio(0);
            }
        }
    }

    // epilogue: combine lq-group partial sums, then ctx = O/(l+EPS) -> Y f16
    #pragma unroll
    for (int f = 0; f < 2; ++f) {
        float tot = lsum[f];
        tot += __shfl_xor(tot, 16);
        tot += __shfl_xor(tot, 32);          // all 4 copies of q=lr now hold row sum
        const int q0 = qb[f] + lq * 4;
        #pragma unroll
        for (int r = 0; r < 4; ++r) {
            const float inv = 1.0f / (__shfl(tot, lq * 4 + r) + 1e-7f);
            #pragma unroll
            for (int nt = 0; nt < 4; ++nt)
                Y[base + (size_t)(q0 + r) * D_ + nt * 16 + lr] = (_Float16)(O[f][nt][r] * inv);
        }
    }
}

// ---------------- launch ----------------

extern "C" void kernel_launch(void* const* d_in, const int* in_sizes, int n_in,
                              void* d_out, int out_size, void* d_ws, size_t ws_size,
                              hipStream_t stream) {
    const float* x  = (const float*)d_in[0];
    const float* Wq = (const float*)d_in[1];
    const float* bq = (const float*)d_in[2];
    const float* Wk = (const float*)d_in[3];
    const float* bk = (const float*)d_in[4];
    const float* Wv = (const float*)d_in[5];
    const float* bv = (const float*)d_in[6];
    const float* Wo = (const float*)d_in[7];
    const float* bo = (const float*)d_in[8];

    // workspace layout (f16): xh 16MB | 4x Wt 2MB (wtq/wtk/wtv contiguous!) |
    // Q,K,Vt,Y 16MB each => 92.3 MB
    char* ws = (char*)d_ws;
    _Float16* xh  = (_Float16*)ws;
    _Float16* wtq = (_Float16*)(ws + (size_t)16777216);
    _Float16* wtk = wtq + 1048576;
    _Float16* wtv = wtk + 1048576;
    _Float16* wto = wtv + 1048576;
    _Float16* Qh  = (_Float16*)(ws + (size_t)16777216 + 4 * (size_t)2097152);
    _Float16* Kh  = Qh + 8388608;
    _Float16* Vth = Kh + 8388608;
    _Float16* Yh  = Vth + 8388608;
    float* out = (float*)d_out;

    cast_x_kernel<<<8192, 256, 0, stream>>>((const float4*)x, (half4v*)xh, 2097152);
    transpose_cast4_kernel<<<dim3(32, 32, 4), dim3(32, 8), 0, stream>>>(
        Wq, Wk, Wv, Wo, wtq, wtk, wtv, wto);

    // fused QKV GEMM: Bt = [wtq;wtk;wtv] (contiguous), N=3072
    gemm_bt_kernel<3><<<dim3(64, 24), 256, 0, stream>>>(
        xh, wtq, bq, bk, bv, Qh, Kh, Vth, 8192, 3072, 1024);

    attn_kernel<<<512, 512, 0, stream>>>(Qh, Kh, Vth, Yh);

    gemm_bt_kernel<0><<<dim3(64, 8), 256, 0, stream>>>(
        Yh, wto, bo, bo, bo, out, out, out, 8192, 1024, 1024);
}

// Round 11
// 246.598 us; speedup vs baseline: 1.1204x; 1.1204x over previous
//
#include <hip/hip_runtime.h>
#include <hip/hip_bf16.h>
#include <cstdint>
#include <cstddef>

// Problem constants
#define B_  4
#define S_  2048
#define D_  1024
#define H_  16
#define HD_ 64

typedef _Float16 half8  __attribute__((ext_vector_type(8)));
typedef _Float16 half4v __attribute__((ext_vector_type(4)));
typedef _Float16 half2v __attribute__((ext_vector_type(2)));
typedef float    f32x4  __attribute__((ext_vector_type(4)));
typedef unsigned int uint2v __attribute__((ext_vector_type(2)));
typedef unsigned int uint4v __attribute__((ext_vector_type(4)));

// async global->LDS, 16B per lane. LDS dest = wave-uniform base + lane*16.
__device__ __forceinline__ void async_copy16(const void* g, void* l) {
    __builtin_amdgcn_global_load_lds(
        (const __attribute__((address_space(1))) unsigned int*)g,
        (__attribute__((address_space(3))) unsigned int*)l,
        16, 0, 0);
}

__device__ __forceinline__ half8 hscale8(half8 v, _Float16 s) {
    #pragma unroll
    for (int i = 0; i < 8; ++i) v[i] *= s;
    return v;
}

// RNE f32x2 -> packed f16x2 (identical numerics to scalar (_Float16) casts)
__device__ __forceinline__ unsigned int pack2(float a, float b) {
    half2v h = { (_Float16)a, (_Float16)b };
    return __builtin_bit_cast(unsigned int, h);
}

// ---------------- prep kernels ----------------

__global__ void cast_x_kernel(const float4* __restrict__ in, half4v* __restrict__ out, int n4) {
    int i = blockIdx.x * 256 + threadIdx.x;
    if (i < n4) {
        float4 v = in[i];
        half4v h = { (_Float16)v.x, (_Float16)v.y, (_Float16)v.z, (_Float16)v.w };
        out[i] = h;
    }
}

// 4x fused: W [K=D][N=D] f32 row-major -> Wt [N][K] f16 row-major
__global__ void transpose_cast4_kernel(
    const float* __restrict__ W0, const float* __restrict__ W1,
    const float* __restrict__ W2, const float* __restrict__ W3,
    _Float16* __restrict__ T0, _Float16* __restrict__ T1,
    _Float16* __restrict__ T2, _Float16* __restrict__ T3)
{
    __shared__ float tile[32][33];
    const float* Wsel[4] = { W0, W1, W2, W3 };
    _Float16*    Tsel[4] = { T0, T1, T2, T3 };
    const float* W  = Wsel[blockIdx.z];
    _Float16*    Wt = Tsel[blockIdx.z];
    const int bn = blockIdx.x * 32, bk = blockIdx.y * 32;
    const int tx = threadIdx.x, ty = threadIdx.y;  // 32x8
    #pragma unroll
    for (int i = 0; i < 32; i += 8)
        tile[ty + i][tx] = W[(size_t)(bk + ty + i) * D_ + bn + tx];
    __syncthreads();
    #pragma unroll
    for (int i = 0; i < 32; i += 8)
        Wt[(size_t)(bn + ty + i) * D_ + bk + tx] = (_Float16)tile[tx][ty + i];
}

// ---------------- GEMM: C = relu(A @ Bt^T + bias) ----------------
// A [M][K] f16, Bt [N][K] f16.
// OUT_MODE: 0 = f32 [M][N] to C0;
//           3 = fused QKV: col segment 0->Q f16 [M][1024] (C0), 1->K f16 (C1),
//               2->V^T per head [(b*16+h)][hd][s] (C2); bias b0/b1/b2 per segment.
// 128x128 tile, BK=64, 256 threads = 4 waves (2x2 of 64x64).
// R3/R8-verified best structure at this shape: 32 KB LDS single-buffer, ~5
// blocks/CU; TLP hides staging (m114 implicit overlap). Measured better than
// drain-dbuf (R4), counted-vmcnt dbuf (R6), and the 256^2 8-phase port (R9:
// 620 TF from 1 block/CU lockstep + 384-block tail at N=3072).
// LDS XOR-swizzled: LDS(row, chunk c) holds global chunk c ^ (row&7) (chunk = 16B).
template<int OUT_MODE>
__global__ __launch_bounds__(256, 2) void gemm_bt_kernel(
    const _Float16* __restrict__ A, const _Float16* __restrict__ Bt,
    const float* __restrict__ b0, const float* __restrict__ b1,
    const float* __restrict__ b2,
    void* __restrict__ C0, void* __restrict__ C1, void* __restrict__ C2,
    int M, int N, int K)
{
    __shared__ _Float16 As[128 * 64];
    __shared__ _Float16 Bs[128 * 64];
    const int tid  = threadIdx.x;
    const int wid  = tid >> 6, lane = tid & 63;
    const int lr   = lane & 15, lq = lane >> 4;
    const int m0   = blockIdx.x * 128, n0 = blockIdx.y * 128;
    const int wm   = (wid >> 1) * 64, wn = (wid & 1) * 64;
    const int srow = tid >> 3;                        // 0..31
    const int csw  = ((tid & 7) ^ (srow & 7)) * 8;    // swizzled source col (halfs)

    f32x4 acc[4][4] = {};

    for (int k0 = 0; k0 < K; k0 += 64) {
        __syncthreads();
        #pragma unroll
        for (int i = 0; i < 4; ++i) {
            async_copy16(A  + (size_t)(m0 + i * 32 + srow) * K + k0 + csw,
                         (char*)As + (i * 256 + wid * 64) * 16);
            async_copy16(Bt + (size_t)(n0 + i * 32 + srow) * K + k0 + csw,
                         (char*)Bs + (i * 256 + wid * 64) * 16);
        }
        __syncthreads();
        #pragma unroll
        for (int ks = 0; ks < 2; ++ks) {
            half8 af[4], bf[4];
            #pragma unroll
            for (int t = 0; t < 4; ++t) {
                af[t] = *(const half8*)(As + (wm + t * 16 + lr) * 64 + (((ks * 4 + lq) ^ (lr & 7)) * 8));
                bf[t] = *(const half8*)(Bs + (wn + t * 16 + lr) * 64 + (((ks * 4 + lq) ^ (lr & 7)) * 8));
            }
            #pragma unroll
            for (int mt = 0; mt < 4; ++mt)
                #pragma unroll
                for (int nt = 0; nt < 4; ++nt)
                    acc[mt][nt] = __builtin_amdgcn_mfma_f32_16x16x32_f16(
                        af[mt], bf[nt], acc[mt][nt], 0, 0, 0);
        }
    }

    // n-segment is uniform per block (128 | 1024)
    const int seg = (OUT_MODE == 3) ? (n0 >> 10) : 0;
    const float* bp = (OUT_MODE == 3) ? (seg == 0 ? b0 : (seg == 1 ? b1 : b2)) : b0;

    #pragma unroll
    for (int mt = 0; mt < 4; ++mt) {
        const int row = m0 + wm + mt * 16 + lq * 4;   // + r
        #pragma unroll
        for (int nt = 0; nt < 4; ++nt) {
            const int col = n0 + wn + nt * 16 + lr;
            const int cl  = (OUT_MODE == 3) ? (col & 1023) : col;
            const float bb = bp[cl];
            if (OUT_MODE == 3 && seg == 2) {
                // V^T per head: [(b*16+h)][hd][s]; 4 consecutive s -> one 8B store
                const int b = row >> 11, sq = row & 2047;
                const int h = cl >> 6, hd = cl & 63;
                half4v o;
                #pragma unroll
                for (int r = 0; r < 4; ++r) {
                    float v = acc[mt][nt][r] + bb;
                    o[r] = (_Float16)(v > 0.0f ? v : 0.0f);
                }
                *(half4v*)((_Float16*)C2 +
                           ((size_t)(b * 16 + h) * 64 + hd) * S_ + sq) = o;
            } else if (OUT_MODE == 3) {
                _Float16* dst = (_Float16*)(seg ? C1 : C0);
                #pragma unroll
                for (int r = 0; r < 4; ++r) {
                    float v = acc[mt][nt][r] + bb;
                    dst[(size_t)(row + r) * 1024 + cl] = (_Float16)(v > 0.0f ? v : 0.0f);
                }
            } else {
                #pragma unroll
                for (int r = 0; r < 4; ++r) {
                    float v = acc[mt][nt][r] + bb;
                    ((float*)C0)[(size_t)(row + r) * N + col] = v > 0.0f ? v : 0.0f;
                }
            }
        }
    }
}

// ---------------- flash attention (4 frags/wave, in-register P, KVBLK=128) ----------------
// R8-verified best (67.4 us, bank conflicts 0, no spill, VGPR 112):
//  - 4 frags/wave, 512 blocks x 256 thr (2 blocks/CU; 4-wave-SIMD variants
//    spill: the live set needs >128 regs -- R1/R10 both confirmed).
//  - KVBLK=128 supertiles halve per-tile fixed costs (R7: 74.5 -> 69.8).
//  - V as two [64][64] half-tiles, 128B rows + chunk^(row&7) swizzle ->
//    zero bank conflicts (R8: 1.64M conflict cycles -> 0, 69.8 -> 67.4).
//  - In-register P: QK^T output -> PV A-operand layout via
//    permlane32_swap + permlane16_swap per 4-lane lq-group (R2/R3).
//  - Fixed-normalizer softmax in log2 domain, bias folded into QK C-in.
//  - p-flip CU balance: co-resident block pairs get complementary work
//    (16-p + 9+p = const); XCD swizzle keeps a head's 8 blocks on one L2.
__global__ __launch_bounds__(256, 2) void attn_kernel(
    const _Float16* __restrict__ Qg, const _Float16* __restrict__ Kg,
    const _Float16* __restrict__ Vtg, _Float16* __restrict__ Y)
{
    __shared__ _Float16 Ks[2][128 * 64];     // K: [key 0..127][hd], 128B rows
    __shared__ _Float16 Vt[2][2][64 * 64];   // V: [half][hd][key-in-half], 128B rows

    // XCD swizzle: a head's 8 blocks share (i&7) -> same XCD L2 caches its K/V.
    const int i  = blockIdx.x;                 // 0..511
    const int bh = ((i & 7) << 3) | (i >> 6);  // 0..63
    const int praw = (i >> 3) & 7;
    const int p  = ((i >> 8) & 1) ? 7 - praw : praw;   // complementary pairing
    const int b  = bh >> 4, h = bh & 15;
    const int tid = threadIdx.x, wid = tid >> 6, lane = tid & 63;
    const int lr = lane & 15, lq = lane >> 4;

    const size_t base  = ((size_t)b * S_) * D_ + (size_t)h * HD_;   // Q/K/Y
    const _Float16* Vh = Vtg + (size_t)bh * 64 * S_;                // V^T head

    const int srow = tid >> 3;                       // 0..31 (8 lanes/row, 8 chunks)
    const int csw  = ((tid & 7) ^ (srow & 7)) * 8;   // swizzled SOURCE col (halfs)

    // 4 fragments per wave: 2 from lo tile (rows 128p+), 2 from hi (1920-128p+)
    const int L = 128 * p, Hh = 1920 - 128 * p;
    const int qb[4] = { L + 16 * wid, L + 64 + 16 * wid,
                        Hh + 16 * wid, Hh + 64 + 16 * wid };
    const int dk[4] = { 2 * p, 2 * p + 1, 30 - 2 * p, 31 - 2 * p };  // diag 64-k tile
    const int nSuper = 16 - p;                                       // 128-k tiles

    // Q fragments (B-operand rows [q][hd]) pre-scaled by log2(e)/8
    half8 aq[4][2];
    #pragma unroll
    for (int f = 0; f < 4; ++f) {
        const _Float16* qp = Qg + base + (size_t)(qb[f] + lr) * D_;
        aq[f][0] = hscale8(*(const half8*)(qp + lq * 8),      (_Float16)0.18033688f);
        aq[f][1] = hscale8(*(const half8*)(qp + 32 + lq * 8), (_Float16)0.18033688f);
    }

    float lsum[4] = {};
    f32x4 O[4][4] = {};

    auto issue_super = [&](int sb) {
        const int bufi = sb & 1;
        // K: 4 calls, rows sb*128 .. +127 (32 rows of 128B per call)
        #pragma unroll
        for (int ii = 0; ii < 4; ++ii)
            async_copy16(Kg + base + (size_t)(sb * 128 + ii * 32 + srow) * D_ + csw,
                         (char*)Ks[bufi] + (ii * 256 + wid * 64) * 16);
        // V: two [64][64] half-tiles, 2 calls each (rows = hd)
        #pragma unroll
        for (int hh = 0; hh < 2; ++hh)
            #pragma unroll
            for (int ii = 0; ii < 2; ++ii)
                async_copy16(Vh + (size_t)(ii * 32 + srow) * S_ + sb * 128 + hh * 64 + csw,
                             (char*)Vt[bufi][hh] + (ii * 256 + wid * 64) * 16);
    };

    issue_super(0);

    for (int sb = 0; sb < nSuper; ++sb) {
        const int cur = sb & 1;
        __syncthreads();   // buf[cur] loads done (issued one iter ago); WAR-safe
        if (sb + 1 < nSuper) issue_super(sb + 1);

        const _Float16* Kc = Ks[cur];

        #pragma unroll
        for (int hh = 0; hh < 2; ++hh) {
            const int kb = sb * 2 + hh;        // 64-key tile index
            const _Float16* Vc = Vt[cur][hh];

            // read kf (K rows) and bv (V^T rows) for this half, shared by frags
            half8 kf[2][4], bv[2][4];
            #pragma unroll
            for (int ks = 0; ks < 2; ++ks)
                #pragma unroll
                for (int tt = 0; tt < 4; ++tt) {
                    kf[ks][tt] = *(const half8*)(Kc + (hh * 64 + tt * 16 + lr) * 64
                                                 + (((ks * 4 + lq) ^ (lr & 7)) * 8));
                    bv[ks][tt] = *(const half8*)(Vc + (tt * 16 + lr) * 64
                                                 + (((ks * 4 + lq) ^ (lr & 7)) * 8));
                }

            #pragma unroll
            for (int f = 0; f < 4; ++f) {
                if (kb > dk[f]) continue;            // frag done (wave-uniform)

                // ---- QK^T (C-in pre-biased with -4*log2e) ----
                f32x4 sc[4];
                #pragma unroll
                for (int tt = 0; tt < 4; ++tt)
                    sc[tt] = f32x4{ -5.770780f, -5.770780f, -5.770780f, -5.770780f };
                __builtin_amdgcn_s_setprio(1);
                #pragma unroll
                for (int ks = 0; ks < 2; ++ks)
                    #pragma unroll
                    for (int tt = 0; tt < 4; ++tt)
                        sc[tt] = __builtin_amdgcn_mfma_f32_16x16x32_f16(kf[ks][tt], aq[f][ks], sc[tt], 0, 0, 0);
                __builtin_amdgcn_s_setprio(0);

                // ---- softmax (fixed normalizer, log2 domain; bias in sc) ----
                const bool diag = (kb == dk[f]);     // wave-uniform
                const int qg = qb[f] + lr;           // this lane's q
                const int kbase = kb * 64 + lq * 4;
                float sum = 0.0f;
                unsigned int pk[4][2];               // pk[t][d]: packed f16x2 of ev
                #pragma unroll
                for (int tt = 0; tt < 4; ++tt) {
                    float ev[4];
                    #pragma unroll
                    for (int r = 0; r < 4; ++r) {
                        float e = __builtin_amdgcn_exp2f(fminf(sc[tt][r], 15.8696f));
                        if (diag)
                            e = (kbase + tt * 16 + r <= qg) ? e : 0.0f;  // causal AFTER exp
                        ev[r] = e;
                        sum += e;
                    }
                    pk[tt][0] = pack2(ev[0], ev[1]);
                    pk[tt][1] = pack2(ev[2], ev[3]);
                }
                lsum[f] += sum;

                // ---- in-register layout exchange (per 4-lane lq-group) ----
                half8 ap[2];
                #pragma unroll
                for (int ks = 0; ks < 2; ++ks) {
                    uint2v s1 = __builtin_amdgcn_permlane32_swap(pk[2 * ks][0], pk[2 * ks + 1][0], false, false);
                    uint2v s2 = __builtin_amdgcn_permlane16_swap(s1[0], s1[1], false, false);
                    uint2v u1 = __builtin_amdgcn_permlane32_swap(pk[2 * ks][1], pk[2 * ks + 1][1], false, false);
                    uint2v u2 = __builtin_amdgcn_permlane16_swap(u1[0], u1[1], false, false);
                    uint4v d = { s2[0], u2[0], s2[1], u2[1] };
                    ap[ks] = __builtin_bit_cast(half8, d);
                }

                // ---- PV ----
                __builtin_amdgcn_s_setprio(1);
                #pragma unroll
                for (int ks = 0; ks < 2; ++ks)
                    #pragma unroll
                    for (int tt = 0; tt < 4; ++tt)
                        O[f][tt] = __builtin_amdgcn_mfma_f32_16x16x32_f16(ap[ks], bv[ks][tt], O[f][tt], 0, 0, 0);
                __builtin_amdgcn_s_setprio(0);
            }
        }
    }

    // epilogue: combine lq-group partial sums, then ctx = O/(l+EPS) -> Y f16
    #pragma unroll
    for (int f = 0; f < 4; ++f) {
        float tot = lsum[f];
        tot += __shfl_xor(tot, 16);
        tot += __shfl_xor(tot, 32);          // all 4 copies of q=lr now hold row sum
        const int q0 = qb[f] + lq * 4;
        #pragma unroll
        for (int r = 0; r < 4; ++r) {
            const float inv = 1.0f / (__shfl(tot, lq * 4 + r) + 1e-7f);
            #pragma unroll
            for (int nt = 0; nt < 4; ++nt)
                Y[base + (size_t)(q0 + r) * D_ + nt * 16 + lr] = (_Float16)(O[f][nt][r] * inv);
        }
    }
}

// ---------------- launch ----------------

extern "C" void kernel_launch(void* const* d_in, const int* in_sizes, int n_in,
                              void* d_out, int out_size, void* d_ws, size_t ws_size,
                              hipStream_t stream) {
    const float* x  = (const float*)d_in[0];
    const float* Wq = (const float*)d_in[1];
    const float* bq = (const float*)d_in[2];
    const float* Wk = (const float*)d_in[3];
    const float* bk = (const float*)d_in[4];
    const float* Wv = (const float*)d_in[5];
    const float* bv = (const float*)d_in[6];
    const float* Wo = (const float*)d_in[7];
    const float* bo = (const float*)d_in[8];

    // workspace layout (f16): xh 16MB | 4x Wt 2MB (wtq/wtk/wtv contiguous!) |
    // Q,K,Vt,Y 16MB each => 92.3 MB
    char* ws = (char*)d_ws;
    _Float16* xh  = (_Float16*)ws;
    _Float16* wtq = (_Float16*)(ws + (size_t)16777216);
    _Float16* wtk = wtq + 1048576;
    _Float16* wtv = wtk + 1048576;
    _Float16* wto = wtv + 1048576;
    _Float16* Qh  = (_Float16*)(ws + (size_t)16777216 + 4 * (size_t)2097152);
    _Float16* Kh  = Qh + 8388608;
    _Float16* Vth = Kh + 8388608;
    _Float16* Yh  = Vth + 8388608;
    float* out = (float*)d_out;

    cast_x_kernel<<<8192, 256, 0, stream>>>((const float4*)x, (half4v*)xh, 2097152);
    transpose_cast4_kernel<<<dim3(32, 32, 4), dim3(32, 8), 0, stream>>>(
        Wq, Wk, Wv, Wo, wtq, wtk, wtv, wto);

    // fused QKV GEMM: Bt = [wtq;wtk;wtv] (contiguous), N=3072
    gemm_bt_kernel<3><<<dim3(64, 24), 256, 0, stream>>>(
        xh, wtq, bq, bk, bv, Qh, Kh, Vth, 8192, 3072, 1024);

    attn_kernel<<<512, 256, 0, stream>>>(Qh, Kh, Vth, Yh);

    gemm_bt_kernel<0><<<dim3(64, 8), 256, 0, stream>>>(
        Yh, wto, bo, bo, bo, out, out, out, 8192, 1024, 1024);
}